// Round 8
// baseline (343.410 us; speedup 1.0000x reference)
//
#include <hip/hip_runtime.h>
#include <stdint.h>

#define S_DIM 8192
#define IN_DIM 4096
#define OUT_DIM 4096
#define K_EXT 128
#define SCALING 0.5f

typedef __attribute__((ext_vector_type(4))) float f32x4;
typedef __attribute__((ext_vector_type(16))) float f32x16;
typedef __attribute__((ext_vector_type(8))) __bf16 bf16x8;

__device__ __forceinline__ unsigned short f2bf(float f) {
    union { float f; uint32_t u; } v; v.f = f;
    uint32_t u = v.u;
    u += 0x7fffu + ((u >> 16) & 1u);   // RNE
    return (unsigned short)(u >> 16);
}

// ---------------- Kernel 1: f32 -> bf16 (grid-stride; used for W and A) ----------------
__global__ __launch_bounds__(256) void convert_w(const float* __restrict__ in,
                                                 unsigned short* __restrict__ out, int n4) {
    int i = blockIdx.x * blockDim.x + threadIdx.x;
    int stride = gridDim.x * blockDim.x;
    for (; i < n4; i += stride) {
        float4 v = ((const float4*)in)[i];
        ushort4 o;
        o.x = f2bf(v.x); o.y = f2bf(v.y); o.z = f2bf(v.z); o.w = f2bf(v.w);
        ((ushort4*)out)[i] = o;
    }
}

// ---------------- Kernel 2: we[o][a*16+r] = bf16(0.5 * B[a][o][r]) ----------------
__global__ __launch_bounds__(256) void build_we(const float* __restrict__ B,
                                                unsigned short* __restrict__ we) {
    int i = blockIdx.x * 256 + threadIdx.x;   // 0..32767 -> (o, a)
    int o = i >> 3, a = i & 7;
    const float* src = B + ((size_t)a * OUT_DIM + o) * 16;
    unsigned short* dst = we + (size_t)o * K_EXT + a * 16;
#pragma unroll
    for (int r = 0; r < 16; r += 4) {
        float4 v = *(const float4*)(src + r);
        ushort4 u;
        u.x = f2bf(SCALING * v.x); u.y = f2bf(SCALING * v.y);
        u.z = f2bf(SCALING * v.z); u.w = f2bf(SCALING * v.w);
        *(ushort4*)(dst + r) = u;
    }
}

// ------- Kernel 3: x f32->bf16 + xe[s][a*16+r] = (a==widx[s]) ? x[s,:].A[a,r,:] : 0 -------
__global__ __launch_bounds__(512) void xak(const float* __restrict__ x,
                                           const unsigned short* __restrict__ Abf,
                                           const int* __restrict__ widx,
                                           unsigned short* __restrict__ xbf,
                                           unsigned short* __restrict__ xe) {
    __shared__ unsigned short xs[32 * 64];    // 4 KB, swizzled
    __shared__ unsigned short as_[128 * 64];  // 16 KB, swizzled
    int s0 = blockIdx.x * 32;
    int t = threadIdx.x;
    int lane = t & 63, w = t >> 6;
    int wr = w & 1, wc = w >> 1;
    int frow = lane & 15, koct = lane >> 4;

    f32x4 acc[2];
#pragma unroll
    for (int n = 0; n < 2; ++n)
#pragma unroll
        for (int j = 0; j < 4; ++j) acc[n][j] = 0.f;

    int xrow = t >> 4, xf4 = t & 15;
    const float* xsrc = x + (size_t)(s0 + xrow) * IN_DIM + xf4 * 4;
    unsigned short* xdst = xbf + (size_t)(s0 + xrow) * IN_DIM + xf4 * 4;
    int xsd = xrow * 64 + ((xf4 * 4) ^ ((xrow & 7) << 3));

    for (int kt = 0; kt < 64; ++kt) {
        int k0 = kt * 64;
        __syncthreads();
        {
            float4 xv = *(const float4*)(xsrc + k0);
            ushort4 o;
            o.x = f2bf(xv.x); o.y = f2bf(xv.y); o.z = f2bf(xv.z); o.w = f2bf(xv.w);
            *(ushort4*)(xdst + k0) = o;
            *(ushort4*)&xs[xsd] = o;
        }
#pragma unroll
        for (int i = 0; i < 2; ++i) {
            int c = i * 512 + t;
            int aj = c >> 3, ch = c & 7;
            bf16x8 av = *(const bf16x8*)(Abf + (size_t)aj * IN_DIM + k0 + ch * 8);
            *(bf16x8*)&as_[aj * 64 + ((ch ^ (aj & 7)) << 3)] = av;
        }
        __syncthreads();
        bf16x8 xf[2], af[2][2];
#pragma unroll
        for (int ks = 0; ks < 2; ++ks) {
            int r = wr * 16 + frow;
            int ch = koct + ks * 4;
            xf[ks] = *(const bf16x8*)&xs[r * 64 + ((ch ^ (r & 7)) << 3)];
        }
#pragma unroll
        for (int nn = 0; nn < 2; ++nn)
#pragma unroll
            for (int ks = 0; ks < 2; ++ks) {
                int rj = wc * 32 + nn * 16 + frow;
                int ch = koct + ks * 4;
                af[nn][ks] = *(const bf16x8*)&as_[rj * 64 + ((ch ^ (rj & 7)) << 3)];
            }
#pragma unroll
        for (int nn = 0; nn < 2; ++nn)
#pragma unroll
            for (int ks = 0; ks < 2; ++ks)
                acc[nn] = __builtin_amdgcn_mfma_f32_16x16x32_bf16(xf[ks], af[nn][ks], acc[nn], 0, 0, 0);
    }
#pragma unroll
    for (int rg = 0; rg < 4; ++rg) {
        int s = s0 + wr * 16 + koct * 4 + rg;
        int aidx = widx[s];
#pragma unroll
        for (int nn = 0; nn < 2; ++nn) {
            int a = wc * 2 + nn;
            unsigned short v = (a == aidx) ? f2bf(acc[nn][rg]) : (unsigned short)0;
            xe[(size_t)s * K_EXT + a * 16 + frow] = v;
        }
    }
}

// ---------------- Kernel 4: 256x256 GEMM over K=4224, 32x32x16 MFMA, counted-vmcnt ----------------
__device__ __forceinline__ void gload_lds16(const void* g, void* l) {
    __builtin_amdgcn_global_load_lds(
        (const __attribute__((address_space(1))) unsigned int*)(uintptr_t)g,
        (__attribute__((address_space(3))) unsigned int*)(unsigned int)(uintptr_t)l,
        16, 0, 0);
}

#define VM4 asm volatile("s_waitcnt vmcnt(4)" ::: "memory")
#define VM2 asm volatile("s_waitcnt vmcnt(2)" ::: "memory")
#define VM0 asm volatile("s_waitcnt vmcnt(0)" ::: "memory")
#define VMNOP do {} while (0)
#define BAR do { __builtin_amdgcn_s_barrier(); asm volatile("" ::: "memory"); } while (0)

// Swizzle: 16B-slot = chunk ^ (row&7) ^ ((row>>3)&3). Rows 8 apart are bank-congruent
// (128B rows) so the 2-bit term keeps 32-row fragment reads conflict-free (2 lanes/quad).
__global__ __launch_bounds__(512, 2) void gemm256(const unsigned short* __restrict__ Xb,
                                                  const unsigned short* __restrict__ Wb,
                                                  const unsigned short* __restrict__ Xe,
                                                  const unsigned short* __restrict__ We,
                                                  const float* __restrict__ bias,
                                                  float* __restrict__ out) {
    extern __shared__ unsigned short lds[];

    const int nT = 512;                      // 32 x 16 tiles, %8==0 -> bijective XCD swizzle
    int bid = blockIdx.x;
    int swz = (bid & 7) * (nT >> 3) + (bid >> 3);
    int tm = swz >> 4, tn = swz & 15;
    int rowBase = tm * 256, colBase = tn * 256;

    int t = threadIdx.x;
    int lane = t & 63;
    int wid = t >> 6;
    int wm = wid >> 2;                       // 0..1 -> 128 rows
    int wn = wid & 3;                        // 0..3 -> 64 cols
    int cL = lane & 31;                      // fragment row/col within 32
    int j5 = lane >> 5;                      // k-octet select
    int wmBase = wm * 128, wnBase = wn * 64;

    // read-side swizzle components (constant across m/n frags: offsets are x32-row multiples)
    int f0 = (cL & 7) ^ ((cL >> 3) & 3);
    int cho[4];
#pragma unroll
    for (int ks = 0; ks < 4; ++ks) cho[ks] = ((2 * ks + j5) ^ f0) << 3;   // element offset

    // staging: thread t -> row t>>3, dest slot t&7; source chunk = slot ^ f(row)
    int srow = t >> 3;
    int schunk = ((t & 7) ^ ((t >> 3) & 7) ^ ((t >> 6) & 3)) << 3;
    const unsigned short* aBase = Xb + (size_t)rowBase * IN_DIM;
    const unsigned short* bBase = Wb + (size_t)colBase * IN_DIM;
    const unsigned short* aeBase = Xe + (size_t)rowBase * K_EXT;
    const unsigned short* beBase = We + (size_t)colBase * K_EXT;
    uint32_t offB_ = (uint32_t)(srow * IN_DIM + schunk);
    uint32_t offE_ = (uint32_t)(srow * K_EXT + schunk);

    f32x16 acc[4][2];
#pragma unroll
    for (int m = 0; m < 4; m++)
#pragma unroll
        for (int n = 0; n < 2; n++)
#pragma unroll
            for (int j = 0; j < 16; j++) acc[m][n][j] = 0.f;

#define RD_A2(P_, KP_, MH_, DST) \
    _Pragma("unroll") for (int m2 = 0; m2 < 2; ++m2) \
      _Pragma("unroll") for (int ks = 0; ks < 2; ++ks) \
        DST[m2][ks] = *(const bf16x8*)&lds[(P_) * 32768 + (wmBase + ((MH_) * 2 + m2) * 32 + cL) * 64 + cho[(KP_) * 2 + ks]];
#define RD_B2(P_, KP_, DST) \
    _Pragma("unroll") for (int nn = 0; nn < 2; ++nn) \
      _Pragma("unroll") for (int ks = 0; ks < 2; ++ks) \
        DST[nn][ks] = *(const bf16x8*)&lds[(P_) * 32768 + 16384 + (wnBase + nn * 32 + cL) * 64 + cho[(KP_) * 2 + ks]];
#define MFMA8(AF, BF, MH_) \
    __builtin_amdgcn_s_setprio(1); \
    _Pragma("unroll") for (int m2 = 0; m2 < 2; ++m2) \
      _Pragma("unroll") for (int nn = 0; nn < 2; ++nn) \
        _Pragma("unroll") for (int ks = 0; ks < 2; ++ks) \
          acc[(MH_) * 2 + m2][nn] = __builtin_amdgcn_mfma_f32_32x32x16_bf16( \
              AF[m2][ks], BF[nn][ks], acc[(MH_) * 2 + m2][nn], 0, 0, 0); \
    __builtin_amdgcn_s_setprio(0);

// Same 4-phase schedule / stage split / wait points as round 6-7 (proven):
// ph0 reads A rows-lo (groups 0/2) + all B; ph1 reads A rows-hi (groups 1/3).
// Stage order A0,A2,B0,B1 | B2,B3,A1,A3; VM2@ph3 publishes first 6, VM4@ph0 the last 2.
#define TILE(P_, Q_, BA_, BB_, OFF_, GS_, KO_, STG_, VMA_, VMB_) do { \
    bf16x8 aF[2][2], bF[2][2]; \
    RD_A2(P_, 0, 0, aF); RD_B2(P_, 0, bF); \
    if (STG_) { gload_lds16((BA_) + (KO_) + (OFF_),                     &lds[(Q_) * 32768 + t * 8]); \
                gload_lds16((BA_) + (KO_) + 2 * (size_t)(GS_) + (OFF_), &lds[(Q_) * 32768 + 8192 + t * 8]); \
                gload_lds16((BB_) + (KO_) + (OFF_),                     &lds[(Q_) * 32768 + 16384 + t * 8]); \
                gload_lds16((BB_) + (KO_) + (size_t)(GS_) + (OFF_),     &lds[(Q_) * 32768 + 20480 + t * 8]); } \
    VMA_; BAR; MFMA8(aF, bF, 0); BAR; \
    RD_A2(P_, 0, 1, aF); \
    if (STG_) { gload_lds16((BB_) + (KO_) + 2 * (size_t)(GS_) + (OFF_), &lds[(Q_) * 32768 + 24576 + t * 8]); \
                gload_lds16((BB_) + (KO_) + 3 * (size_t)(GS_) + (OFF_), &lds[(Q_) * 32768 + 28672 + t * 8]); \
                gload_lds16((BA_) + (KO_) + (size_t)(GS_) + (OFF_),     &lds[(Q_) * 32768 + 4096 + t * 8]); \
                gload_lds16((BA_) + (KO_) + 3 * (size_t)(GS_) + (OFF_), &lds[(Q_) * 32768 + 12288 + t * 8]); } \
    BAR; MFMA8(aF, bF, 1); BAR; \
    RD_A2(P_, 1, 0, aF); RD_B2(P_, 1, bF); \
    BAR; MFMA8(aF, bF, 0); BAR; \
    RD_A2(P_, 1, 1, aF); \
    VMB_; BAR; MFMA8(aF, bF, 1); BAR; \
  } while (0)

#define GSB ((size_t)64 * IN_DIM)

    // prologue: stage tile 0 into buf 0 (order A0,A2,B0..B3,A1,A3), publish first 6
    gload_lds16(aBase + offB_,                         &lds[t * 8]);
    gload_lds16(aBase + (size_t)128 * IN_DIM + offB_,  &lds[8192 + t * 8]);
    gload_lds16(bBase + offB_,                         &lds[16384 + t * 8]);
    gload_lds16(bBase + (size_t)64 * IN_DIM + offB_,   &lds[20480 + t * 8]);
    gload_lds16(bBase + (size_t)128 * IN_DIM + offB_,  &lds[24576 + t * 8]);
    gload_lds16(bBase + (size_t)192 * IN_DIM + offB_,  &lds[28672 + t * 8]);
    gload_lds16(aBase + (size_t)64 * IN_DIM + offB_,   &lds[4096 + t * 8]);
    gload_lds16(aBase + (size_t)192 * IN_DIM + offB_,  &lds[12288 + t * 8]);
    VM2; BAR;

    int kel = 0;
#pragma unroll 1
    for (int it = 0; it < 31; ++it) {        // tiles 0..61, staging 1..62 (all base)
        TILE(0, 1, aBase, bBase, offB_, GSB, kel + 64, 1, VM4, VM2); kel += 64;
        TILE(1, 0, aBase, bBase, offB_, GSB, kel + 64, 1, VM4, VM2); kel += 64;
    }
    // tail: all source selections compile-time
    TILE(0, 1, aBase, bBase, offB_, GSB, 4032, 1, VM4, VM2);     // tile 62, stages base tile 63
    TILE(1, 0, aeBase, beBase, offE_, 8192, 0, 1, VM4, VM2);     // tile 63, stages ext tile 64
    TILE(0, 1, aeBase, beBase, offE_, 8192, 64, 1, VM4, VM2);    // tile 64, stages ext tile 65
    TILE(1, 0, aBase, bBase, offB_, GSB, 0, 0, VM0, VMNOP);      // tile 65, last

    // ---- epilogue: out = acc + bias; C/D map col=lane&31, row=(reg&3)+8*(reg>>2)+4*(lane>>5) ----
    float bv0 = bias[colBase + wnBase + cL];
    float bv1 = bias[colBase + wnBase + 32 + cL];
#pragma unroll
    for (int m = 0; m < 4; ++m) {
#pragma unroll
        for (int rg = 0; rg < 16; ++rg) {
            int row = rowBase + wmBase + m * 32 + j5 * 4 + (rg & 3) + (rg >> 2) * 8;
            float* orow = out + (size_t)row * OUT_DIM + colBase + wnBase;
            orow[cL] = acc[m][0][rg] + bv0;
            orow[32 + cL] = acc[m][1][rg] + bv1;
        }
    }
}

extern "C" void kernel_launch(void* const* d_in, const int* in_sizes, int n_in,
                              void* d_out, int out_size, void* d_ws, size_t ws_size,
                              hipStream_t stream) {
    const float* x = (const float*)d_in[0];
    const float* W = (const float*)d_in[1];
    const float* bias = (const float*)d_in[2];
    const float* Abuf = (const float*)d_in[3];
    const float* Bbuf = (const float*)d_in[4];   // [1, A, OUT, R]
    const int* widx = (const int*)d_in[5];
    float* out = (float*)d_out;

    size_t xbf_elems = (size_t)S_DIM * IN_DIM;
    size_t wbf_elems = (size_t)OUT_DIM * IN_DIM;
    size_t abf_elems = (size_t)8 * 16 * IN_DIM;
    size_t xe_elems = (size_t)S_DIM * K_EXT;
    size_t we_elems = (size_t)OUT_DIM * K_EXT;
    size_t need = (xbf_elems + wbf_elems + abf_elems + xe_elems + we_elems) * 2;
    if (ws_size < need) return;

    unsigned short* xbf = (unsigned short*)d_ws;
    unsigned short* wbf = xbf + xbf_elems;
    unsigned short* abf = wbf + wbf_elems;
    unsigned short* xe = abf + abf_elems;
    unsigned short* we = xe + xe_elems;

    hipFuncSetAttribute(reinterpret_cast<const void*>(gemm256),
                        hipFuncAttributeMaxDynamicSharedMemorySize, 131072);

    convert_w<<<2048, 256, 0, stream>>>(W, wbf, (int)(wbf_elems / 4));
    convert_w<<<512, 256, 0, stream>>>(Abuf, abf, (int)(abf_elems / 4));
    build_we<<<128, 256, 0, stream>>>(Bbuf, we);
    xak<<<256, 512, 0, stream>>>(x, abf, widx, xbf, xe);
    gemm256<<<512, 512, 131072, stream>>>(xbf, wbf, xe, we, bias, out);
}

// Round 9
// 341.480 us; speedup vs baseline: 1.0057x; 1.0057x over previous
//
#include <hip/hip_runtime.h>
#include <stdint.h>

#define S_DIM 8192
#define IN_DIM 4096
#define OUT_DIM 4096
#define K_EXT 128
#define SCALING 0.5f

typedef __attribute__((ext_vector_type(4))) float f32x4;
typedef __attribute__((ext_vector_type(8))) __bf16 bf16x8;

__device__ __forceinline__ unsigned short f2bf(float f) {
    union { float f; uint32_t u; } v; v.f = f;
    uint32_t u = v.u;
    u += 0x7fffu + ((u >> 16) & 1u);   // RNE
    return (unsigned short)(u >> 16);
}

// ---------------- Kernel 1: f32 -> bf16 (grid-stride; used for W and A) ----------------
__global__ __launch_bounds__(256) void convert_w(const float* __restrict__ in,
                                                 unsigned short* __restrict__ out, int n4) {
    int i = blockIdx.x * blockDim.x + threadIdx.x;
    int stride = gridDim.x * blockDim.x;
    for (; i < n4; i += stride) {
        float4 v = ((const float4*)in)[i];
        ushort4 o;
        o.x = f2bf(v.x); o.y = f2bf(v.y); o.z = f2bf(v.z); o.w = f2bf(v.w);
        ((ushort4*)out)[i] = o;
    }
}

// ---------------- Kernel 2: we[o][a*16+r] = bf16(0.5 * B[a][o][r]) ----------------
__global__ __launch_bounds__(256) void build_we(const float* __restrict__ B,
                                                unsigned short* __restrict__ we) {
    int i = blockIdx.x * 256 + threadIdx.x;   // 0..32767 -> (o, a)
    int o = i >> 3, a = i & 7;
    const float* src = B + ((size_t)a * OUT_DIM + o) * 16;
    unsigned short* dst = we + (size_t)o * K_EXT + a * 16;
#pragma unroll
    for (int r = 0; r < 16; r += 4) {
        float4 v = *(const float4*)(src + r);
        ushort4 u;
        u.x = f2bf(SCALING * v.x); u.y = f2bf(SCALING * v.y);
        u.z = f2bf(SCALING * v.z); u.w = f2bf(SCALING * v.w);
        *(ushort4*)(dst + r) = u;
    }
}

// ------- Kernel 3: x f32->bf16 + xe[s][a*16+r] = (a==widx[s]) ? x[s,:].A[a,r,:] : 0 -------
__global__ __launch_bounds__(512) void xak(const float* __restrict__ x,
                                           const unsigned short* __restrict__ Abf,
                                           const int* __restrict__ widx,
                                           unsigned short* __restrict__ xbf,
                                           unsigned short* __restrict__ xe) {
    __shared__ unsigned short xs[32 * 64];    // 4 KB, swizzled
    __shared__ unsigned short as_[128 * 64];  // 16 KB, swizzled
    int s0 = blockIdx.x * 32;
    int t = threadIdx.x;
    int lane = t & 63, w = t >> 6;
    int wr = w & 1, wc = w >> 1;
    int frow = lane & 15, koct = lane >> 4;

    f32x4 acc[2];
#pragma unroll
    for (int n = 0; n < 2; ++n)
#pragma unroll
        for (int j = 0; j < 4; ++j) acc[n][j] = 0.f;

    int xrow = t >> 4, xf4 = t & 15;
    const float* xsrc = x + (size_t)(s0 + xrow) * IN_DIM + xf4 * 4;
    unsigned short* xdst = xbf + (size_t)(s0 + xrow) * IN_DIM + xf4 * 4;
    int xsd = xrow * 64 + ((xf4 * 4) ^ ((xrow & 7) << 3));

    for (int kt = 0; kt < 64; ++kt) {
        int k0 = kt * 64;
        __syncthreads();
        {
            float4 xv = *(const float4*)(xsrc + k0);
            ushort4 o;
            o.x = f2bf(xv.x); o.y = f2bf(xv.y); o.z = f2bf(xv.z); o.w = f2bf(xv.w);
            *(ushort4*)(xdst + k0) = o;
            *(ushort4*)&xs[xsd] = o;
        }
#pragma unroll
        for (int i = 0; i < 2; ++i) {
            int c = i * 512 + t;
            int aj = c >> 3, ch = c & 7;
            bf16x8 av = *(const bf16x8*)(Abf + (size_t)aj * IN_DIM + k0 + ch * 8);
            *(bf16x8*)&as_[aj * 64 + ((ch ^ (aj & 7)) << 3)] = av;
        }
        __syncthreads();
        bf16x8 xf[2], af[2][2];
#pragma unroll
        for (int ks = 0; ks < 2; ++ks) {
            int r = wr * 16 + frow;
            int ch = koct + ks * 4;
            xf[ks] = *(const bf16x8*)&xs[r * 64 + ((ch ^ (r & 7)) << 3)];
        }
#pragma unroll
        for (int nn = 0; nn < 2; ++nn)
#pragma unroll
            for (int ks = 0; ks < 2; ++ks) {
                int rj = wc * 32 + nn * 16 + frow;
                int ch = koct + ks * 4;
                af[nn][ks] = *(const bf16x8*)&as_[rj * 64 + ((ch ^ (rj & 7)) << 3)];
            }
#pragma unroll
        for (int nn = 0; nn < 2; ++nn)
#pragma unroll
            for (int ks = 0; ks < 2; ++ks)
                acc[nn] = __builtin_amdgcn_mfma_f32_16x16x32_bf16(xf[ks], af[nn][ks], acc[nn], 0, 0, 0);
    }
#pragma unroll
    for (int rg = 0; rg < 4; ++rg) {
        int s = s0 + wr * 16 + koct * 4 + rg;
        int aidx = widx[s];
#pragma unroll
        for (int nn = 0; nn < 2; ++nn) {
            int a = wc * 2 + nn;
            unsigned short v = (a == aidx) ? f2bf(acc[nn][rg]) : (unsigned short)0;
            xe[(size_t)s * K_EXT + a * 16 + frow] = v;
        }
    }
}

// ------- Kernel 4: 256x256 GEMM over K=4224, BK=32, depth-3 prefetch, 1 vmcnt/tile -------
// LDS: 4 buffers x 32KB. Per buffer: A = 128 rows x 128B (row j holds logical rows j, j+128),
// B same. 16B slot within row = ((hi<<2)|kchunk) ^ (j&7)  [hi = logical_row>>7].
__device__ __forceinline__ void gload_lds16(const void* g, void* l) {
    __builtin_amdgcn_global_load_lds(
        (const __attribute__((address_space(1))) unsigned int*)(uintptr_t)g,
        (__attribute__((address_space(3))) unsigned int*)(unsigned int)(uintptr_t)l,
        16, 0, 0);
}

#define VM8 asm volatile("s_waitcnt vmcnt(8)" ::: "memory")
#define VM4 asm volatile("s_waitcnt vmcnt(4)" ::: "memory")
#define VM0 asm volatile("s_waitcnt vmcnt(0)" ::: "memory")
#define VMNOP do {} while (0)
#define BAR do { __builtin_amdgcn_s_barrier(); asm volatile("" ::: "memory"); } while (0)

__global__ __launch_bounds__(512, 2) void gemm256(const unsigned short* __restrict__ Xb,
                                                  const unsigned short* __restrict__ Wb,
                                                  const unsigned short* __restrict__ Xe,
                                                  const unsigned short* __restrict__ We,
                                                  const float* __restrict__ bias,
                                                  float* __restrict__ out) {
    extern __shared__ unsigned short lds[];

    const int nT = 512;                      // 32 x 16 tiles, %8==0 -> bijective XCD swizzle
    int bid = blockIdx.x;
    int swz = (bid & 7) * (nT >> 3) + (bid >> 3);
    int tm = swz >> 4, tn = swz & 15;
    int rowBase = tm * 256, colBase = tn * 256;

    int t = threadIdx.x;
    int lane = t & 63;
    int wid = t >> 6;
    int wm = wid >> 2;                       // 0..1 -> 128 rows
    int wn = wid & 3;                        // 0..3 -> 64 cols
    int frow = lane & 15;
    int koct = lane >> 4;                    // k-chunk 0..3 (BK=32)
    int wmBase = wm * 128, wnBase = wn * 64;

    // ---- read-side base pointers (slot is per-thread constant) ----
    int slotA = ((wm << 2) | koct) ^ (frow & 7);
    int slotB = (((wn >> 1) << 2) | koct) ^ (frow & 7);
    const unsigned short* pA = lds + frow * 64 + slotA * 8;                       // + P*16384 + MH*4096 + mm*1024
    const unsigned short* pB = lds + 8192 + (wn & 1) * 4096 + frow * 64 + slotB * 8;  // + P*16384 + nn*1024

    // ---- staging per-lane source offsets (inverse-swizzled) ----
    int sg = (t & 7) ^ ((t >> 3) & 7);              // sigma = pre-swizzle slot
    int rr = (t >> 3) + ((sg >> 2) << 7);           // logical row for load 0
    int cc = (sg & 3) << 3;                         // k elem offset
    uint32_t oB0 = (uint32_t)(rr * IN_DIM + cc);    // base-K A/B load0
    uint32_t oB1 = oB0 + 64 * IN_DIM;               // load1 (rows +64)
    uint32_t oE0 = (uint32_t)(rr * K_EXT + cc);     // ext-K
    uint32_t oE1 = oE0 + 64 * K_EXT;
    const unsigned short* aBase = Xb + (size_t)rowBase * IN_DIM;
    const unsigned short* bBase = Wb + (size_t)colBase * IN_DIM;
    const unsigned short* aeBase = Xe + (size_t)rowBase * K_EXT;
    const unsigned short* beBase = We + (size_t)colBase * K_EXT;

    f32x4 acc[8][4];
#pragma unroll
    for (int m = 0; m < 8; m++)
#pragma unroll
        for (int n = 0; n < 4; n++)
#pragma unroll
            for (int j = 0; j < 4; j++) acc[m][n][j] = 0.f;

#define RDA(P_, MH_, DST) \
    _Pragma("unroll") for (int mm = 0; mm < 4; ++mm) \
      DST[mm] = *(const bf16x8*)(pA + (P_) * 16384 + (MH_) * 4096 + mm * 1024);
#define RDB(P_, DST) \
    _Pragma("unroll") for (int nn = 0; nn < 4; ++nn) \
      DST[nn] = *(const bf16x8*)(pB + (P_) * 16384 + nn * 1024);
#define MFMA16(AF, BF, MH_) \
    __builtin_amdgcn_s_setprio(1); \
    _Pragma("unroll") for (int mm = 0; mm < 4; ++mm) \
      _Pragma("unroll") for (int nn = 0; nn < 4; ++nn) \
        acc[(MH_) * 4 + mm][nn] = __builtin_amdgcn_mfma_f32_16x16x32_bf16( \
            AF[mm], BF[nn], acc[(MH_) * 4 + mm][nn], 0, 0, 0); \
    __builtin_amdgcn_s_setprio(0);

#define STAGE32(Q_, BA_, BB_, O0_, O1_, KO_) do { \
    gload_lds16((BA_) + (KO_) + (O0_), &lds[(Q_) * 16384 + t * 8]); \
    gload_lds16((BA_) + (KO_) + (O1_), &lds[(Q_) * 16384 + 4096 + t * 8]); \
    gload_lds16((BB_) + (KO_) + (O0_), &lds[(Q_) * 16384 + 8192 + t * 8]); \
    gload_lds16((BB_) + (KO_) + (O1_), &lds[(Q_) * 16384 + 12288 + t * 8]); \
  } while (0)

// One K=32 tile from buffer P_, optionally staging tile t+3 into Q_.
// vmcnt invariant: entering a tile, 8 loads outstanding (tiles t+1, t+2).
// ph0 stages 4 (-> 12); late VM8 drains tile t+1's 4 before the closing barrier.
#define TILE32(P_, Q_, BA_, BB_, O0_, O1_, KO_, STG_, VMOP_) do { \
    bf16x8 aF[4], bF[4]; \
    RDA(P_, 0, aF); RDB(P_, bF); \
    if (STG_) STAGE32(Q_, BA_, BB_, O0_, O1_, KO_); \
    BAR; MFMA16(aF, bF, 0); BAR; \
    RDA(P_, 1, aF); \
    BAR; MFMA16(aF, bF, 1); \
    VMOP_; BAR; \
  } while (0)

    // prologue: stage tiles 0,1,2 into bufs 0,1,2 (12 loads); publish tile 0
    STAGE32(0, aBase, bBase, oB0, oB1, 0);
    STAGE32(1, aBase, bBase, oB0, oB1, 32);
    STAGE32(2, aBase, bBase, oB0, oB1, 64);
    VM8; BAR;

    int kel = 0;
#pragma unroll 1
    for (int it = 0; it < 31; ++it) {        // tiles 0..123, staging 3..126 (base)
        TILE32(0, 3, aBase, bBase, oB0, oB1, kel + 96, 1, VM8); kel += 32;
        TILE32(1, 0, aBase, bBase, oB0, oB1, kel + 96, 1, VM8); kel += 32;
        TILE32(2, 1, aBase, bBase, oB0, oB1, kel + 96, 1, VM8); kel += 32;
        TILE32(3, 2, aBase, bBase, oB0, oB1, kel + 96, 1, VM8); kel += 32;
    }
    // tail: tiles 124..131 (ext staging / drain), all source selections compile-time
    TILE32(0, 3, aBase, bBase, oB0, oB1, 4064, 1, VM8);       // 124 stages base 127
    TILE32(1, 0, aeBase, beBase, oE0, oE1, 0, 1, VM8);        // 125 stages ext 128
    TILE32(2, 1, aeBase, beBase, oE0, oE1, 32, 1, VM8);       // 126 stages ext 129
    TILE32(3, 2, aeBase, beBase, oE0, oE1, 64, 1, VM8);       // 127 stages ext 130
    TILE32(0, 3, aeBase, beBase, oE0, oE1, 96, 1, VM8);       // 128 stages ext 131
    TILE32(1, 0, aBase, bBase, oB0, oB1, 0, 0, VM4);          // 129 (publish 130)
    TILE32(2, 0, aBase, bBase, oB0, oB1, 0, 0, VM0);          // 130 (publish 131)
    TILE32(3, 0, aBase, bBase, oB0, oB1, 0, 0, VMNOP);        // 131

    // ---- epilogue: out = acc + bias (16x16 C/D map: col=lane&15 via frow, rows koct*4+rg) ----
    int rquad = koct << 2;
    float biasv[4];
#pragma unroll
    for (int n = 0; n < 4; n++) biasv[n] = bias[colBase + wnBase + n * 16 + frow];

#pragma unroll
    for (int m = 0; m < 8; m++) {
#pragma unroll
        for (int rg = 0; rg < 4; rg++) {
            int lr = wmBase + (m >> 2) * 64 + (m & 3) * 16 + rquad + rg;
            float* orow = out + (size_t)(rowBase + lr) * OUT_DIM;
#pragma unroll
            for (int n = 0; n < 4; n++) {
                int lc = wnBase + n * 16 + frow;
                orow[colBase + lc] = acc[m][n][rg] + biasv[n];
            }
        }
    }
}

extern "C" void kernel_launch(void* const* d_in, const int* in_sizes, int n_in,
                              void* d_out, int out_size, void* d_ws, size_t ws_size,
                              hipStream_t stream) {
    const float* x = (const float*)d_in[0];
    const float* W = (const float*)d_in[1];
    const float* bias = (const float*)d_in[2];
    const float* Abuf = (const float*)d_in[3];
    const float* Bbuf = (const float*)d_in[4];   // [1, A, OUT, R]
    const int* widx = (const int*)d_in[5];
    float* out = (float*)d_out;

    size_t xbf_elems = (size_t)S_DIM * IN_DIM;
    size_t wbf_elems = (size_t)OUT_DIM * IN_DIM;
    size_t abf_elems = (size_t)8 * 16 * IN_DIM;
    size_t xe_elems = (size_t)S_DIM * K_EXT;
    size_t we_elems = (size_t)OUT_DIM * K_EXT;
    size_t need = (xbf_elems + wbf_elems + abf_elems + xe_elems + we_elems) * 2;
    if (ws_size < need) return;

    unsigned short* xbf = (unsigned short*)d_ws;
    unsigned short* wbf = xbf + xbf_elems;
    unsigned short* abf = wbf + wbf_elems;
    unsigned short* xe = abf + abf_elems;
    unsigned short* we = xe + xe_elems;

    hipFuncSetAttribute(reinterpret_cast<const void*>(gemm256),
                        hipFuncAttributeMaxDynamicSharedMemorySize, 131072);

    convert_w<<<2048, 256, 0, stream>>>(W, wbf, (int)(wbf_elems / 4));
    convert_w<<<512, 256, 0, stream>>>(Abuf, abf, (int)(abf_elems / 4));
    build_we<<<128, 256, 0, stream>>>(Bbuf, we);
    xak<<<256, 512, 0, stream>>>(x, abf, widx, xbf, xe);
    gemm256<<<512, 512, 131072, stream>>>(xbf, wbf, xe, we, bias, out);
}

// Round 11
// 333.609 us; speedup vs baseline: 1.0294x; 1.0236x over previous
//
#include <hip/hip_runtime.h>
#include <stdint.h>

#define S_DIM 8192
#define IN_DIM 4096
#define OUT_DIM 4096
#define K_EXT 128
#define SCALING 0.5f

typedef __attribute__((ext_vector_type(4))) float f32x4;
typedef __attribute__((ext_vector_type(8))) __bf16 bf16x8;

__device__ __forceinline__ unsigned short f2bf(float f) {
    union { float f; uint32_t u; } v; v.f = f;
    uint32_t u = v.u;
    u += 0x7fffu + ((u >> 16) & 1u);   // RNE
    return (unsigned short)(u >> 16);
}

// ---------------- Kernel 1: f32 -> bf16 (grid-stride; used for W and A) ----------------
__global__ __launch_bounds__(256) void convert_w(const float* __restrict__ in,
                                                 unsigned short* __restrict__ out, int n4) {
    int i = blockIdx.x * blockDim.x + threadIdx.x;
    int stride = gridDim.x * blockDim.x;
    for (; i < n4; i += stride) {
        float4 v = ((const float4*)in)[i];
        ushort4 o;
        o.x = f2bf(v.x); o.y = f2bf(v.y); o.z = f2bf(v.z); o.w = f2bf(v.w);
        ((ushort4*)out)[i] = o;
    }
}

// ---------------- Kernel 2: we[o][a*16+r] = bf16(0.5 * B[a][o][r]) ----------------
__global__ __launch_bounds__(256) void build_we(const float* __restrict__ B,
                                                unsigned short* __restrict__ we) {
    int i = blockIdx.x * 256 + threadIdx.x;   // 0..32767 -> (o, a)
    int o = i >> 3, a = i & 7;
    const float* src = B + ((size_t)a * OUT_DIM + o) * 16;
    unsigned short* dst = we + (size_t)o * K_EXT + a * 16;
#pragma unroll
    for (int r = 0; r < 16; r += 4) {
        float4 v = *(const float4*)(src + r);
        ushort4 u;
        u.x = f2bf(SCALING * v.x); u.y = f2bf(SCALING * v.y);
        u.z = f2bf(SCALING * v.z); u.w = f2bf(SCALING * v.w);
        *(ushort4*)(dst + r) = u;
    }
}

// ------- Kernel 3: x f32->bf16 + xe[s][a*16+r] = (a==widx[s]) ? x[s,:].A[a,r,:] : 0 -------
__global__ __launch_bounds__(512) void xak(const float* __restrict__ x,
                                           const unsigned short* __restrict__ Abf,
                                           const int* __restrict__ widx,
                                           unsigned short* __restrict__ xbf,
                                           unsigned short* __restrict__ xe) {
    __shared__ unsigned short xs[32 * 64];    // 4 KB, swizzled
    __shared__ unsigned short as_[128 * 64];  // 16 KB, swizzled
    int s0 = blockIdx.x * 32;
    int t = threadIdx.x;
    int lane = t & 63, w = t >> 6;
    int wr = w & 1, wc = w >> 1;
    int frow = lane & 15, koct = lane >> 4;

    f32x4 acc[2];
#pragma unroll
    for (int n = 0; n < 2; ++n)
#pragma unroll
        for (int j = 0; j < 4; ++j) acc[n][j] = 0.f;

    int xrow = t >> 4, xf4 = t & 15;
    const float* xsrc = x + (size_t)(s0 + xrow) * IN_DIM + xf4 * 4;
    unsigned short* xdst = xbf + (size_t)(s0 + xrow) * IN_DIM + xf4 * 4;
    int xsd = xrow * 64 + ((xf4 * 4) ^ ((xrow & 7) << 3));

    for (int kt = 0; kt < 64; ++kt) {
        int k0 = kt * 64;
        __syncthreads();
        {
            float4 xv = *(const float4*)(xsrc + k0);
            ushort4 o;
            o.x = f2bf(xv.x); o.y = f2bf(xv.y); o.z = f2bf(xv.z); o.w = f2bf(xv.w);
            *(ushort4*)(xdst + k0) = o;
            *(ushort4*)&xs[xsd] = o;
        }
#pragma unroll
        for (int i = 0; i < 2; ++i) {
            int c = i * 512 + t;
            int aj = c >> 3, ch = c & 7;
            bf16x8 av = *(const bf16x8*)(Abf + (size_t)aj * IN_DIM + k0 + ch * 8);
            *(bf16x8*)&as_[aj * 64 + ((ch ^ (aj & 7)) << 3)] = av;
        }
        __syncthreads();
        bf16x8 xf[2], af[2][2];
#pragma unroll
        for (int ks = 0; ks < 2; ++ks) {
            int r = wr * 16 + frow;
            int ch = koct + ks * 4;
            xf[ks] = *(const bf16x8*)&xs[r * 64 + ((ch ^ (r & 7)) << 3)];
        }
#pragma unroll
        for (int nn = 0; nn < 2; ++nn)
#pragma unroll
            for (int ks = 0; ks < 2; ++ks) {
                int rj = wc * 32 + nn * 16 + frow;
                int ch = koct + ks * 4;
                af[nn][ks] = *(const bf16x8*)&as_[rj * 64 + ((ch ^ (rj & 7)) << 3)];
            }
#pragma unroll
        for (int nn = 0; nn < 2; ++nn)
#pragma unroll
            for (int ks = 0; ks < 2; ++ks)
                acc[nn] = __builtin_amdgcn_mfma_f32_16x16x32_bf16(xf[ks], af[nn][ks], acc[nn], 0, 0, 0);
    }
#pragma unroll
    for (int rg = 0; rg < 4; ++rg) {
        int s = s0 + wr * 16 + koct * 4 + rg;
        int aidx = widx[s];
#pragma unroll
        for (int nn = 0; nn < 2; ++nn) {
            int a = wc * 2 + nn;
            unsigned short v = (a == aidx) ? f2bf(acc[nn][rg]) : (unsigned short)0;
            xe[(size_t)s * K_EXT + a * 16 + frow] = v;
        }
    }
}

// ------- Kernel 4: 256x256 GEMM over K=4224, kh-split halves, 1 half-tile stage/phase, vmcnt(6) -------
// LDS: 2 buffers x 64KB. Per buffer (shorts): A-kh0 @0, B-kh0 @8192, A-kh1 @16384, B-kh1 @24576.
// Each half: 128 LDS-rows x 128B; LDS-row j holds logical rows j, j+128;
// 16B slot = ((hi<<2)|kchunk) ^ (j&7)  [hi = logical_row>>7]. 0-conflict (R9-verified).
__device__ __forceinline__ void gload_lds16(const void* g, void* l) {
    __builtin_amdgcn_global_load_lds(
        (const __attribute__((address_space(1))) unsigned int*)(uintptr_t)g,
        (__attribute__((address_space(3))) unsigned int*)(unsigned int)(uintptr_t)l,
        16, 0, 0);
}

#define VM8 asm volatile("s_waitcnt vmcnt(8)" ::: "memory")
#define VM6 asm volatile("s_waitcnt vmcnt(6)" ::: "memory")
#define VM4 asm volatile("s_waitcnt vmcnt(4)" ::: "memory")
#define VM0 asm volatile("s_waitcnt vmcnt(0)" ::: "memory")
#define VMNOP do {} while (0)
#define BAR do { __builtin_amdgcn_s_barrier(); asm volatile("" ::: "memory"); } while (0)

__global__ __launch_bounds__(512, 2) void gemm256(const unsigned short* __restrict__ Xb,
                                                  const unsigned short* __restrict__ Wb,
                                                  const unsigned short* __restrict__ Xe,
                                                  const unsigned short* __restrict__ We,
                                                  const float* __restrict__ bias,
                                                  float* __restrict__ out) {
    extern __shared__ unsigned short lds[];

    const int nT = 512;                      // 32 x 16 tiles, %8==0 -> bijective XCD swizzle
    int bid = blockIdx.x;
    int swz = (bid & 7) * (nT >> 3) + (bid >> 3);
    int tm = swz >> 4, tn = swz & 15;
    int rowBase = tm * 256, colBase = tn * 256;

    int t = threadIdx.x;
    int lane = t & 63;
    int wid = t >> 6;
    int wm = wid >> 2;                       // 0..1 -> 128 rows
    int wn = wid & 3;                        // 0..3 -> 64 cols
    int frow = lane & 15;
    int koct = lane >> 4;                    // k-chunk 0..3 within a 32-k half
    int wmBase = wm * 128, wnBase = wn * 64;

    // ---- read-side base pointers (per-parity; all ds_read offsets are immediates) ----
    int slotA = ((wm << 2) | koct) ^ (frow & 7);
    int slotB = (((wn >> 1) << 2) | koct) ^ (frow & 7);
    const unsigned short* pA0 = lds + frow * 64 + slotA * 8;
    const unsigned short* pA1 = pA0 + 32768;
    const unsigned short* pB0 = lds + 8192 + (wn & 1) * 4096 + frow * 64 + slotB * 8;
    const unsigned short* pB1 = pB0 + 32768;

    // ---- staging per-lane source offsets (inverse-swizzled; R9-verified) ----
    int sg = (t & 7) ^ ((t >> 3) & 7);              // pre-swizzle slot
    int rr = (t >> 3) + ((sg >> 2) << 7);           // logical row for gload 0
    int cc = (sg & 3) << 3;                         // k elem offset within half
    uint32_t oB0 = (uint32_t)(rr * IN_DIM + cc);
    uint32_t oB1 = oB0 + 64 * IN_DIM;
    uint32_t oE0 = (uint32_t)(rr * K_EXT + cc);
    uint32_t oE1 = oE0 + 64 * K_EXT;
    const unsigned short* aBase = Xb + (size_t)rowBase * IN_DIM;
    const unsigned short* bBase = Wb + (size_t)colBase * IN_DIM;
    const unsigned short* aeBase = Xe + (size_t)rowBase * K_EXT;
    const unsigned short* beBase = We + (size_t)colBase * K_EXT;

    f32x4 acc[8][4];
#pragma unroll
    for (int m = 0; m < 8; m++)
#pragma unroll
        for (int n = 0; n < 4; n++)
#pragma unroll
            for (int j = 0; j < 4; j++) acc[m][n][j] = 0.f;

#define RDA(P_, KH_, MH_, DST) \
    _Pragma("unroll") for (int mm = 0; mm < 4; ++mm) \
      DST[mm] = *(const bf16x8*)(pA##P_ + (KH_) * 16384 + (MH_) * 4096 + mm * 1024);
#define RDB(P_, KH_, DST) \
    _Pragma("unroll") for (int nn = 0; nn < 4; ++nn) \
      DST[nn] = *(const bf16x8*)(pB##P_ + (KH_) * 16384 + nn * 1024);
#define MFMA16(AF, BF, MH_) \
    __builtin_amdgcn_s_setprio(1); \
    _Pragma("unroll") for (int mm = 0; mm < 4; ++mm) \
      _Pragma("unroll") for (int nn = 0; nn < 4; ++nn) \
        acc[(MH_) * 4 + mm][nn] = __builtin_amdgcn_mfma_f32_16x16x32_bf16( \
            AF[mm], BF[nn], acc[(MH_) * 4 + mm][nn], 0, 0, 0); \
    __builtin_amdgcn_s_setprio(0);

// stage one half (2 gloads, 16KB): BASE + KO + {O0,O1} -> lds[LDSO + {0,4096} + t*8]
#define STG(BASE_, O0_, O1_, KO_, LDSO_) do { \
    gload_lds16((BASE_) + (KO_) + (O0_), &lds[(LDSO_) + t * 8]); \
    gload_lds16((BASE_) + (KO_) + (O1_), &lds[(LDSO_) + 4096 + t * 8]); \
  } while (0)

// Tile T (buf P_). Stage plan (1 half/phase, 3 halves in flight):
//   ph0: Akh1(T+1)->buf[P^1]+16384   ph1: Bkh1(T+1)->buf[P^1]+24576
//   ph2: Akh0(T+2)->buf[P]+0         ph3: Bkh0(T+2)->buf[P]+8192
// Publishes (verified): T ph0's VM6+BAR completes through Bkh1(T) (read at ph2/ph3);
// T ph2's VM6+BAR completes through Bkh0(T+1) (read at T+1 ph0/ph1).
// Reads per phase 8/4/8/4 with B-frag reuse; 16 MFMA per phase; double barrier.
#define TILE(P_, A1_, B1_, X0_, X1_, K1_, S1_, A2_, B2_, Y0_, Y1_, K2_, S2_, VA_, VB_) do { \
    bf16x8 aF[4], bF[4]; \
    RDA(P_, 0, 0, aF); RDB(P_, 0, bF); \
    if (S1_) STG(A1_, X0_, X1_, K1_, ((P_ ^ 1) * 32768 + 16384)); \
    VA_; BAR; MFMA16(aF, bF, 0); BAR; \
    RDA(P_, 0, 1, aF); \
    if (S1_) STG(B1_, X0_, X1_, K1_, ((P_ ^ 1) * 32768 + 24576)); \
    BAR; MFMA16(aF, bF, 1); BAR; \
    RDA(P_, 1, 0, aF); RDB(P_, 1, bF); \
    if (S2_) STG(A2_, Y0_, Y1_, K2_, ((P_) * 32768 + 0)); \
    VB_; BAR; MFMA16(aF, bF, 0); BAR; \
    RDA(P_, 1, 1, aF); \
    if (S2_) STG(B2_, Y0_, Y1_, K2_, ((P_) * 32768 + 8192)); \
    BAR; MFMA16(aF, bF, 1); BAR; \
  } while (0)

    // prologue: 6 halves in steady-state issue order: Akh0(0),Bkh0(0),Akh1(0),Bkh1(0),Akh0(1),Bkh0(1)
    STG(aBase, oB0, oB1, 0, 0);
    STG(bBase, oB0, oB1, 0, 8192);
    STG(aBase, oB0, oB1, 32, 16384);
    STG(bBase, oB0, oB1, 32, 24576);
    STG(aBase, oB0, oB1, 64, 32768);
    STG(bBase, oB0, oB1, 64, 40960);
    VM8; BAR;   // publish kh0(0); leave kh1(0)+kh0(1) in flight = steady-state entry

    int kel = 0;
#pragma unroll 1
    for (int it = 0; it < 31; ++it) {        // tiles 0..61 (base staging throughout)
        TILE(0, aBase, bBase, oB0, oB1, kel + 96, 1, aBase, bBase, oB0, oB1, kel + 128, 1, VM6, VM6); kel += 64;
        TILE(1, aBase, bBase, oB0, oB1, kel + 96, 1, aBase, bBase, oB0, oB1, kel + 128, 1, VM6, VM6); kel += 64;
    }
    // tail (tiles 62..65); all source selections compile-time
    TILE(0, aBase, bBase, oB0, oB1, 4064, 1, aeBase, beBase, oE0, oE1, 0, 1, VM6, VM6);   // 62
    TILE(1, aeBase, beBase, oE0, oE1, 32, 1, aeBase, beBase, oE0, oE1, 64, 1, VM6, VM6);  // 63
    TILE(0, aeBase, beBase, oE0, oE1, 96, 1, aBase, bBase, oB0, oB1, 0, 0, VM6, VM4);     // 64: VM4@ph2 publishes kh0(65)
    TILE(1, aBase, bBase, oB0, oB1, 0, 0, aBase, bBase, oB0, oB1, 0, 0, VM0, VMNOP);      // 65: VM0@ph0 publishes kh1(65)

    // ---- epilogue: out = acc + bias ----
    int rquad = koct << 2;
    float biasv[4];
#pragma unroll
    for (int n = 0; n < 4; n++) biasv[n] = bias[colBase + wnBase + n * 16 + frow];

#pragma unroll
    for (int m = 0; m < 8; m++) {
#pragma unroll
        for (int rg = 0; rg < 4; rg++) {
            int lr = wmBase + (m >> 2) * 64 + (m & 3) * 16 + rquad + rg;
            float* orow = out + (size_t)(rowBase + lr) * OUT_DIM;
#pragma unroll
            for (int n = 0; n < 4; n++) {
                int lc = wnBase + n * 16 + frow;
                orow[colBase + lc] = acc[m][n][rg] + biasv[n];
            }
        }
    }
}

extern "C" void kernel_launch(void* const* d_in, const int* in_sizes, int n_in,
                              void* d_out, int out_size, void* d_ws, size_t ws_size,
                              hipStream_t stream) {
    const float* x = (const float*)d_in[0];
    const float* W = (const float*)d_in[1];
    const float* bias = (const float*)d_in[2];
    const float* Abuf = (const float*)d_in[3];
    const float* Bbuf = (const float*)d_in[4];   // [1, A, OUT, R]
    const int* widx = (const int*)d_in[5];
    float* out = (float*)d_out;

    size_t xbf_elems = (size_t)S_DIM * IN_DIM;
    size_t wbf_elems = (size_t)OUT_DIM * IN_DIM;
    size_t abf_elems = (size_t)8 * 16 * IN_DIM;
    size_t xe_elems = (size_t)S_DIM * K_EXT;
    size_t we_elems = (size_t)OUT_DIM * K_EXT;
    size_t need = (xbf_elems + wbf_elems + abf_elems + xe_elems + we_elems) * 2;
    if (ws_size < need) return;

    unsigned short* xbf = (unsigned short*)d_ws;
    unsigned short* wbf = xbf + xbf_elems;
    unsigned short* abf = wbf + wbf_elems;
    unsigned short* xe = abf + abf_elems;
    unsigned short* we = xe + xe_elems;

    hipFuncSetAttribute(reinterpret_cast<const void*>(gemm256),
                        hipFuncAttributeMaxDynamicSharedMemorySize, 131072);

    convert_w<<<2048, 256, 0, stream>>>(W, wbf, (int)(wbf_elems / 4));
    convert_w<<<512, 256, 0, stream>>>(Abuf, abf, (int)(abf_elems / 4));
    build_we<<<128, 256, 0, stream>>>(Bbuf, we);
    xak<<<256, 512, 0, stream>>>(x, abf, widx, xbf, xe);
    gemm256<<<512, 512, 131072, stream>>>(xbf, wbf, xe, we, bias, out);
}